// Round 12
// baseline (221.437 us; speedup 1.0000x reference)
//
#include <hip/hip_runtime.h>
#include <cstddef>

// D,H,W,C = 10,200,176,64; convs: (s2,p1) -> (s1,p(0,1,1)) -> (s2,p1)
// Activations channels-last fp16, pixel = 128 B, CHUNK-SWIZZLED within pixel:
//   16B chunk s of pixel at column P stored at position s ^ (P & 7).
// Weights pre-swizzled by co (chunk s of row co at s ^ (co & 7)), staged to
// LDS per kd (B crosses L1/L2 once per block per kd).
//
// R11 -> R12: MEGA-PHASE. Eleven structures all land conv1 at 43-53 us with
// ~4,100 cyc/tap vs an LDS-read floor of ~1,900 -- half of every tap is the
// per-tap phase machinery (2 barriers + vmcnt wait + lgkm full-drain, x18
// per kd). Fix: stage A + ALL 9 B taps per kd (72 KB), one vmcnt(0)+barrier,
// then a barrier-FREE 9-tap span (180 ds_reads + 432 MFMA per wave, compiler
// free to interleave across tap boundaries), one lgkm-drain+barrier at kd
// end. Barriers/kd: 18 -> 2. LDS 138,240 -> 1 block/CU (R10 proved >64KB
// static works); LDS caps residency anyway so launch_bounds(256,1) frees the
// allocator to 512 regs (no R8-style spill: watch WRITE_SIZE ~22MB).
#define HH 200
#define WW 176
#define HP 202
#define WP 178
#define D_IN 10
#define D1 5
#define D2 3
#define D3 2
#define SLICE ((size_t)HP * WP * 64)

#define LBALL_BYTES (9 * 8192)

typedef _Float16 h8 __attribute__((ext_vector_type(8)));
typedef float f4 __attribute__((ext_vector_type(4)));

__device__ __forceinline__ void gl_lds16(const void* g, void* l) {
    __builtin_amdgcn_global_load_lds(
        (const __attribute__((address_space(1))) void*)g,
        (__attribute__((address_space(3))) void*)l, 16, 0, 0);
}

// ---- prep: halo-zero A2/A3 + weight transform (3 sets) + winner, one launch
// blocks [0,8): halo; [8, 8+1296): wtrans; [1304, ...): winner
__global__ __launch_bounds__(256) void prep_k(const float* __restrict__ W1,
                                              const float* __restrict__ W2,
                                              const float* __restrict__ W3,
                                              _Float16* __restrict__ wdst,
                                              _Float16* __restrict__ A2,
                                              _Float16* __restrict__ A3,
                                              const int* __restrict__ coors,
                                              int* __restrict__ winner, int nvox) {
    const int b = blockIdx.x;
    if (b < 8) {
        _Float16* base = (b < D1) ? (A2 + (size_t)b * SLICE) : (A3 + (size_t)(b - D1) * SLICE);
        const h8 z = {};
        for (int t = threadIdx.x; t < 6080; t += 256) {
            size_t off;
            if (t < 2848) {
                int r = t / 1424, c = t - r * 1424;
                off = (size_t)(r ? (HP - 1) : 0) * WP * 64 + (size_t)c * 8;
            } else {
                int u = t - 2848;
                int c = u / 1616, v = u - c * 1616;
                int hr = v >> 3, o = v & 7;
                off = ((size_t)hr * WP + (c ? (WP - 1) : 0)) * 64 + (size_t)o * 8;
            }
            *(h8*)(base + off) = z;
        }
    } else if (b < 8 + 1296) {
        // OIDHW fp32 -> [set][tap][co][ci swizzled] fp16 (B staged verbatim,
        // chunk s of row co stored at s ^ (co & 7) for conflict-free LDS reads)
        int idx = (b - 8) * 256 + threadIdx.x;
        if (idx < 3 * 27 * 64 * 64) {
            int set = idx / 110592;
            int r = idx - set * 110592;
            const float* src = set == 0 ? W1 : (set == 1 ? W2 : W3);
            int ci = r & 63;
            int co = (r >> 6) & 63;
            int tap = r >> 12;
            int s = ci >> 3, j = ci & 7;
            wdst[set * 110592 + tap * 4096 + co * 64 + (((s ^ (co & 7)) << 3) | j)] =
                (_Float16)src[(co * 64 + ci) * 27 + tap];
        }
    } else {
        int v = (b - 1304) * 256 + threadIdx.x;
        if (v < nvox) {
            int d = coors[v * 4 + 1], h = coors[v * 4 + 2], w = coors[v * 4 + 3];
            atomicMax(&winner[(d * HH + h) * WW + w], v + 1);
        }
    }
}

__global__ __launch_bounds__(256) void scatter_k(const float* __restrict__ feat,
                                                 const int* __restrict__ coors,
                                                 const int* __restrict__ winner,
                                                 _Float16* __restrict__ A, int nvox) {
    int v = blockIdx.x * 4 + (threadIdx.x >> 6);
    int ci = threadIdx.x & 63;
    if (v >= nvox) return;
    int d = coors[v * 4 + 1], h = coors[v * 4 + 2], w = coors[v * 4 + 3];
    if (winner[(d * HH + h) * WW + w] != v + 1) return;
    int P = w + 1;
    int swz = (((ci >> 3) ^ (P & 7)) << 3) | (ci & 7);
    A[(size_t)d * SLICE + ((size_t)(h + 1) * WP + P) * 64 + swz] = (_Float16)feat[v * 64 + ci];
}

// ---- MFMA conv: 4-wave block, RPW rows/wave, per-kd mega-phase ------------
// Block = 4 waves; wave i -> RPW output rows, 48 px, 64 co.
// Per kd: stage A ((4*RPW+2) rows, NSTG glds) + B all 9 taps (72 glds);
// vmcnt(0); barrier; 9 taps of pure {ds_read + MFMA} with NO syncs (compiler
// interleaves across taps); lgkmcnt(0); barrier (WAR guard for next stage).
// mfma_f32_16x16x32_f16: A[m=lane&15][k=quad*8+j], D: co=lane&15, px=quad*4+reg
template <int FINAL, int RPW>
__global__ __launch_bounds__(256, 1) void conv_mfma_k(
    const _Float16* __restrict__ in, void* __restrict__ outp,
    const _Float16* __restrict__ wt,
    const float* __restrict__ scale, const float* __restrict__ bias,
    int inD, int strideD, int padD) {
    constexpr int BROWS = 4 * RPW;                  // output rows per block
    constexpr int AR = BROWS + 2;                   // staged input rows
    constexpr int NSTG = (AR * 400 + 63) / 64;      // A chunks: 63 / 38
    constexpr int LA = NSTG * 1024;                 // 64512 / 38912 (incl pad)
    constexpr int CMAX = AR * 400 - 1;

    __shared__ char smem_raw[LA + LBALL_BYTES];     // 138,240 / 112,640 -> 1 blk/CU
    _Float16* la = (_Float16*)smem_raw;
    char* lball = smem_raw + LA;

    const int lane = threadIdx.x & 63;
    const int wave = threadIdx.x >> 6;   // 0..3
    const int l16 = lane & 15;
    const int quad = lane >> 4;
    const int h0 = blockIdx.y * BROWS;
    const int wb = blockIdx.x * 48;      // 48 | 8 so (wb+px)&7 == px&7
    const int d = blockIdx.z;

    int kd_lo = padD - d * strideD; if (kd_lo < 0) kd_lo = 0;
    int kd_hi = inD - 1 - d * strideD + padD; if (kd_hi > 2) kd_hi = 2;

    f4 acc[RPW][3][4];
#pragma unroll
    for (int rr = 0; rr < RPW; ++rr)
#pragma unroll
        for (int mt = 0; mt < 3; ++mt)
#pragma unroll
            for (int nt = 0; nt < 4; ++nt) acc[rr][mt][nt] = (f4){0.f, 0.f, 0.f, 0.f};

    for (int kd = kd_lo; kd <= kd_hi; ++kd) {
        const int zd = d * strideD + kd - padD;
        const _Float16* __restrict__ aplane = in + (size_t)zd * SLICE;
        const _Float16* __restrict__ wkd = wt + (size_t)kd * 9 * 4096;

        // stage A: AR rows x 50 px x 8 chunks -> NSTG instrs over 4 waves
        // (WAR vs previous kd's reads guarded by the kd-end drained barrier)
        for (int j = wave; j < NSTG; j += 4) {
            int c = j * 64 + lane;
            if (c > CMAX) c = CMAX;            // dup into pad
            int r = c / 400;
            int rem = c - r * 400;
            int px = rem >> 3, s = rem & 7;
            int g = wb + px; if (g > 177) g = 177;  // ragged edge dup
            gl_lds16(aplane + ((size_t)(h0 + r) * WP + g) * 64 + s * 8,
                     smem_raw + j * 1024);
        }
        // stage B: ALL 9 taps, 72 x 1KB chunks over 4 waves (18 instrs/wave)
#pragma unroll
        for (int i = 0; i < 18; ++i) {
            int k = i * 4 + wave;
            gl_lds16(wkd + (size_t)k * 512 + (size_t)lane * 8, lball + k * 1024);
        }
        asm volatile("s_waitcnt vmcnt(0)" ::: "memory");  // all stages landed
        __builtin_amdgcn_sched_barrier(0);
        __builtin_amdgcn_s_barrier();
        __builtin_amdgcn_sched_barrier(0);

        // 9-tap barrier-free span: compiler interleaves reads/MFMA freely
        __builtin_amdgcn_s_setprio(1);
#pragma unroll
        for (int t = 0; t < 9; ++t) {    // tap = kh*3 + kw
            const int kh = t / 3;
            const int kw = t - 3 * kh;
            const _Float16* lb = (const _Float16*)(lball + t * 8192);
#pragma unroll
            for (int ch = 0; ch < 2; ++ch) {
                const int q = ch * 4 + quad;
                h8 b[4];
#pragma unroll
                for (int nt = 0; nt < 4; ++nt)
                    b[nt] = *(const h8*)(lb + (nt * 16 + l16) * 64 +
                                         ((q ^ (l16 & 7)) << 3));
#pragma unroll
                for (int rr = 0; rr < RPW; ++rr) {
                    const int row = wave * RPW + rr + kh;
#pragma unroll
                    for (int mt = 0; mt < 3; ++mt) {
                        const int px = mt * 16 + l16 + kw;
                        h8 a = *(const h8*)(la + ((size_t)row * 50 + px) * 64 +
                                            ((q ^ (px & 7)) << 3));
#pragma unroll
                        for (int nt = 0; nt < 4; ++nt)
                            acc[rr][mt][nt] = __builtin_amdgcn_mfma_f32_16x16x32_f16(
                                a, b[nt], acc[rr][mt][nt], 0, 0, 0);
                    }
                }
            }
        }
        __builtin_amdgcn_s_setprio(0);
        // drain this wave's ds_reads BEFORE signaling: after the barrier,
        // every wave's reads of la/lball are complete -> safe to restage.
        asm volatile("s_waitcnt lgkmcnt(0)" ::: "memory");
        __builtin_amdgcn_sched_barrier(0);
        __builtin_amdgcn_s_barrier();    // WAR guard: la/lball reusable
        __builtin_amdgcn_sched_barrier(0);
    }

    // epilogue: scale+bias+relu; D layout: co=l16(+nt*16), px=mt*16+quad*4+reg
    // (kd-end drained barrier => all waves' LDS reads complete)
    if (FINAL) {
#pragma unroll
        for (int nt = 0; nt < 4; ++nt) {
            const int co = nt * 16 + l16;
            const float s = scale[co];
            const float bb = bias[co];
#pragma unroll
            for (int rr = 0; rr < RPW; ++rr) {
                const int h = h0 + wave * RPW + rr;
#pragma unroll
                for (int mt = 0; mt < 3; ++mt) {
                    const int w0 = wb + mt * 16 + quad * 4;  // multiple of 4
                    if (w0 < WW) {
                        f4 v;
#pragma unroll
                        for (int r = 0; r < 4; ++r) {
                            float x = acc[rr][mt][nt][r] * s + bb;
                            v[r] = x > 0.f ? x : 0.f;
                        }
                        *(f4*)((float*)outp + (((size_t)(co * 2 + d)) * HH + h) * WW + w0) = v;
                    }
                }
            }
        }
    } else {
        // LDS bounce: transpose to fp16 rows, then coalesced 1-KB stores.
        // Per h-row region: 48 px x 72 shorts; BROWS x 6,912 B <= LA.
        _Float16* epb = (_Float16*)smem_raw;
#pragma unroll
        for (int nt = 0; nt < 4; ++nt) {
            const int co = nt * 16 + l16;
            const float s = scale[co];
            const float bb = bias[co];
#pragma unroll
            for (int rr = 0; rr < RPW; ++rr) {
                _Float16* ep = epb + (size_t)(wave * RPW + rr) * (48 * 72);
#pragma unroll
                for (int mt = 0; mt < 3; ++mt) {
#pragma unroll
                    for (int r = 0; r < 4; ++r) {
                        float x = acc[rr][mt][nt][r] * s + bb;
                        x = x > 0.f ? x : 0.f;
                        ep[(mt * 16 + quad * 4 + r) * 72 + co] = (_Float16)x;
                    }
                }
            }
        }
        __builtin_amdgcn_s_barrier();    // (paranoia: ep writes of all waves)
        const int lim = (WW - wb) * 8;   // chunk count; 256 for wb=144 else >=384
#pragma unroll
        for (int rr = 0; rr < RPW; ++rr) {
            const int h = h0 + wave * RPW + rr;
            const _Float16* ep = epb + (size_t)(wave * RPW + rr) * (48 * 72);
#pragma unroll
            for (int cv = 0; cv < 6; ++cv) {
                if (cv * 64 < lim) {
                    const int c2 = cv * 64 + lane;
                    const int pxl = c2 >> 3, s = c2 & 7;
                    h8 v = *(const h8*)(ep + pxl * 72 + s * 8);
                    const int P = wb + pxl + 1;
                    *(h8*)((_Float16*)outp + (size_t)d * SLICE +
                           ((size_t)(h + 1) * WP + P) * 64 + ((s ^ (P & 7)) << 3)) = v;
                }
            }
        }
    }
}

// ---------------- launch ---------------------------------------------------
extern "C" void kernel_launch(void* const* d_in, const int* in_sizes, int n_in,
                              void* d_out, int out_size, void* d_ws, size_t ws_size,
                              hipStream_t stream) {
    const float* feat   = (const float*)d_in[0];
    const int*   coors  = (const int*)d_in[1];
    const float* W1     = (const float*)d_in[3];
    const float* scale1 = (const float*)d_in[4];
    const float* bias1  = (const float*)d_in[5];
    const float* W2     = (const float*)d_in[6];
    const float* scale2 = (const float*)d_in[7];
    const float* bias2  = (const float*)d_in[8];
    const float* W3     = (const float*)d_in[9];
    const float* scale3 = (const float*)d_in[10];
    const float* bias3  = (const float*)d_in[11];
    const int nvox = in_sizes[0] / 64;

    // workspace: [A1][win][A2][A3][wt x3]; memset covers A1+win only
    const size_t nA1 = (size_t)D_IN * SLICE;     // fp16 elems
    const size_t nWin = (size_t)D_IN * HH * WW;  // ints
    const size_t nA2 = (size_t)D1 * SLICE;
    const size_t nA3 = (size_t)D2 * SLICE;
    const size_t nWT = (size_t)27 * 64 * 64;     // fp16 elems per set

    _Float16* A1 = (_Float16*)d_ws;
    int* win = (int*)(A1 + nA1);
    _Float16* A2 = (_Float16*)(win + nWin);
    _Float16* A3 = A2 + nA2;
    _Float16* wt1 = A3 + nA3;
    _Float16* wt2 = wt1 + nWT;
    _Float16* wt3 = wt2 + nWT;

    hipMemsetAsync(d_ws, 0, nA1 * sizeof(_Float16) + nWin * sizeof(int), stream);

    const int win_blk = (nvox + 255) / 256;
    prep_k<<<8 + 1296 + win_blk, 256, 0, stream>>>(W1, W2, W3, wt1, A2, A3,
                                                   coors, win, nvox);
    scatter_k<<<(nvox + 3) / 4, 256, 0, stream>>>(feat, coors, win, A1, nvox);

    dim3 blk(256);
    // conv1: A1(10) -> A2(5)   RPW=2: 8-row blocks, 500 blocks @ 1/CU
    conv_mfma_k<0, 2><<<dim3(4, 25, D1), blk, 0, stream>>>(A1, A2, wt1, scale1, bias1, D_IN, 2, 1);
    // conv2: A2(5) -> A3(3)    RPW=1: 4-row blocks, 600 blocks
    conv_mfma_k<0, 1><<<dim3(4, 50, D2), blk, 0, stream>>>(A2, A3, wt2, scale2, bias2, D1, 1, 0);
    // conv3: A3(3) -> out planar fp32  RPW=1: 400 blocks
    conv_mfma_k<1, 1><<<dim3(4, 50, D3), blk, 0, stream>>>(A3, (float*)d_out, wt3, scale3, bias3, D2, 2, 1);
}

// Round 13
// 187.201 us; speedup vs baseline: 1.1829x; 1.1829x over previous
//
#include <hip/hip_runtime.h>
#include <cstddef>

// D,H,W,C = 10,200,176,64; convs: (s2,p1) -> (s1,p(0,1,1)) -> (s2,p1)
// Activations channels-last fp16, pixel = 128 B, CHUNK-SWIZZLED within pixel:
//   16B chunk s of pixel at column P stored at position s ^ (P & 7).
// Weights re-packed [set][tap][q=ci>>3][co][j=ci&7] fp16: each MFMA B-fragment
// is a contiguous 16 B global load (L1-resident; every wave reads the whole
// 8 KB tap anyway, so LDS staging of B bought no within-wave reuse).
//
// R12 -> R13: TWO-FLOOR FIX. Budget per CU for conv1: MFMA-array ~46K cyc,
// LDS-array ~47K cyc (R9's 20 ds_read_b128 per 48 MFMA); measured 104K cyc
// wall = the floors barely overlap. Remove the LDS floor instead of the sync:
//  * kw-major tap span: per (kw,ch) read 12 A frags ONCE into regs (4 rows x
//    3 mt -- identical px range for all 3 kh taps) and reuse across kh.
//    LDS reads per kd-span: 180 -> 72 per wave (floor 47K -> ~19K cyc).
//  * B straight global->VGPR per (kh): 4x16B L1-hit loads, software-pipelined
//    one kh ahead; wave-private => the whole 9-tap span is BARRIER-FREE.
//  * 2 blocks/CU x 4 waves (A-only LDS 64.5 KB) = 8 waves/CU: the TLP that
//    R12's mega-phase lacked; launch_bounds(256,2) = 256-reg budget so the
//    pipeline isn't strangled like R1/R4's 64-reg B-in-VGPR attempts.
// A staging + kd-boundary sync identical to the R11-verified skeleton.
#define HH 200
#define WW 176
#define HP 202
#define WP 178
#define D_IN 10
#define D1 5
#define D2 3
#define D3 2
#define SLICE ((size_t)HP * WP * 64)

typedef _Float16 h8 __attribute__((ext_vector_type(8)));
typedef float f4 __attribute__((ext_vector_type(4)));

__device__ __forceinline__ void gl_lds16(const void* g, void* l) {
    __builtin_amdgcn_global_load_lds(
        (const __attribute__((address_space(1))) void*)g,
        (__attribute__((address_space(3))) void*)l, 16, 0, 0);
}

// ---- prep: halo-zero A2/A3 + weight transform (3 sets) + winner, one launch
// blocks [0,8): halo; [8, 8+1296): wtrans; [1304, ...): winner
__global__ __launch_bounds__(256) void prep_k(const float* __restrict__ W1,
                                              const float* __restrict__ W2,
                                              const float* __restrict__ W3,
                                              _Float16* __restrict__ wdst,
                                              _Float16* __restrict__ A2,
                                              _Float16* __restrict__ A3,
                                              const int* __restrict__ coors,
                                              int* __restrict__ winner, int nvox) {
    const int b = blockIdx.x;
    if (b < 8) {
        _Float16* base = (b < D1) ? (A2 + (size_t)b * SLICE) : (A3 + (size_t)(b - D1) * SLICE);
        const h8 z = {};
        for (int t = threadIdx.x; t < 6080; t += 256) {
            size_t off;
            if (t < 2848) {
                int r = t / 1424, c = t - r * 1424;
                off = (size_t)(r ? (HP - 1) : 0) * WP * 64 + (size_t)c * 8;
            } else {
                int u = t - 2848;
                int c = u / 1616, v = u - c * 1616;
                int hr = v >> 3, o = v & 7;
                off = ((size_t)hr * WP + (c ? (WP - 1) : 0)) * 64 + (size_t)o * 8;
            }
            *(h8*)(base + off) = z;
        }
    } else if (b < 8 + 1296) {
        // OIDHW fp32 -> [set][tap][q=ci>>3][co][j=ci&7] fp16 (contiguous B frags)
        int idx = (b - 8) * 256 + threadIdx.x;
        if (idx < 3 * 27 * 64 * 64) {
            int set = idx / 110592;
            int r = idx - set * 110592;
            const float* src = set == 0 ? W1 : (set == 1 ? W2 : W3);
            int ci = r & 63;
            int co = (r >> 6) & 63;
            int tap = r >> 12;
            wdst[set * 110592 + tap * 4096 + (ci >> 3) * 512 + co * 8 + (ci & 7)] =
                (_Float16)src[(co * 64 + ci) * 27 + tap];
        }
    } else {
        int v = (b - 1304) * 256 + threadIdx.x;
        if (v < nvox) {
            int d = coors[v * 4 + 1], h = coors[v * 4 + 2], w = coors[v * 4 + 3];
            atomicMax(&winner[(d * HH + h) * WW + w], v + 1);
        }
    }
}

__global__ __launch_bounds__(256) void scatter_k(const float* __restrict__ feat,
                                                 const int* __restrict__ coors,
                                                 const int* __restrict__ winner,
                                                 _Float16* __restrict__ A, int nvox) {
    int v = blockIdx.x * 4 + (threadIdx.x >> 6);
    int ci = threadIdx.x & 63;
    if (v >= nvox) return;
    int d = coors[v * 4 + 1], h = coors[v * 4 + 2], w = coors[v * 4 + 3];
    if (winner[(d * HH + h) * WW + w] != v + 1) return;
    int P = w + 1;
    int swz = (((ci >> 3) ^ (P & 7)) << 3) | (ci & 7);
    A[(size_t)d * SLICE + ((size_t)(h + 1) * WP + P) * 64 + swz] = (_Float16)feat[v * 64 + ci];
}

// ---- MFMA conv: 4-wave block, RPW rows/wave, kw-major reg-reuse span ------
// Block = 4 waves; wave i -> RPW output rows, 48 px, 64 co.
// Per kd: stage A ((4*RPW+2) rows x 50 px, NSTG glds over 4 waves);
// vmcnt(0)+barrier; then barrier-free span: for kw, for ch: {load B(kh=0);
// read 3*(RPW+2) A frags; load B(kh=1); MFMA kh=0; load B(kh=2); MFMA kh=1;
// MFMA kh=2}; lgkm(0)+barrier (WAR for next kd restage).
// mfma_f32_16x16x32_f16: A[m=lane&15][k=quad*8+j], D: co=lane&15, px=quad*4+reg
template <int FINAL, int RPW>
__global__ __launch_bounds__(256, 2) void conv_mfma_k(
    const _Float16* __restrict__ in, void* __restrict__ outp,
    const _Float16* __restrict__ wt,
    const float* __restrict__ scale, const float* __restrict__ bias,
    int inD, int strideD, int padD) {
    constexpr int BROWS = 4 * RPW;                  // output rows per block
    constexpr int AR = BROWS + 2;                   // staged input rows
    constexpr int NSTG = (AR * 400 + 63) / 64;      // A chunks: 63 / 38
    constexpr int LA = NSTG * 1024;                 // 64512 / 38912 (incl pad)
    constexpr int CMAX = AR * 400 - 1;

    __shared__ char smem_raw[LA];                   // A only: 2 blocks/CU
    _Float16* la = (_Float16*)smem_raw;

    const int lane = threadIdx.x & 63;
    const int wave = threadIdx.x >> 6;   // 0..3
    const int l16 = lane & 15;
    const int quad = lane >> 4;
    const int h0 = blockIdx.y * BROWS;
    const int wb = blockIdx.x * 48;      // 48 | 8 so (wb+px)&7 == px&7
    const int d = blockIdx.z;

    int kd_lo = padD - d * strideD; if (kd_lo < 0) kd_lo = 0;
    int kd_hi = inD - 1 - d * strideD + padD; if (kd_hi > 2) kd_hi = 2;

    f4 acc[RPW][3][4];
#pragma unroll
    for (int rr = 0; rr < RPW; ++rr)
#pragma unroll
        for (int mt = 0; mt < 3; ++mt)
#pragma unroll
            for (int nt = 0; nt < 4; ++nt) acc[rr][mt][nt] = (f4){0.f, 0.f, 0.f, 0.f};

    for (int kd = kd_lo; kd <= kd_hi; ++kd) {
        const int zd = d * strideD + kd - padD;
        const _Float16* __restrict__ aplane = in + (size_t)zd * SLICE;
        const _Float16* __restrict__ wkd = wt + (size_t)kd * 9 * 4096;

        // stage A: AR rows x 50 px x 8 chunks -> NSTG instrs over 4 waves
        // (WAR vs previous kd's reads guarded by the kd-end drained barrier)
        for (int j = wave; j < NSTG; j += 4) {
            int c = j * 64 + lane;
            if (c > CMAX) c = CMAX;            // dup into pad
            int r = c / 400;
            int rem = c - r * 400;
            int px = rem >> 3, s = rem & 7;
            int g = wb + px; if (g > 177) g = 177;  // ragged edge dup
            gl_lds16(aplane + ((size_t)(h0 + r) * WP + g) * 64 + s * 8,
                     smem_raw + j * 1024);
        }
        asm volatile("s_waitcnt vmcnt(0)" ::: "memory");  // A landed
        __builtin_amdgcn_sched_barrier(0);
        __builtin_amdgcn_s_barrier();
        __builtin_amdgcn_sched_barrier(0);

        // barrier-free 9-tap span, kw-major with A-register reuse across kh
        __builtin_amdgcn_s_setprio(1);
#pragma unroll
        for (int kw = 0; kw < 3; ++kw) {
#pragma unroll
            for (int ch = 0; ch < 2; ++ch) {
                const int q = ch * 4 + quad;
                h8 b[3][4];
                // B(kh=0) first: flies under the A ds_reads below
#pragma unroll
                for (int nt = 0; nt < 4; ++nt)
                    b[0][nt] = *(const h8*)(wkd + (size_t)kw * 4096 + (q << 9) +
                                            ((nt * 16 + l16) << 3));
                // A group: (RPW+2) rows x 3 mt, reused across all 3 kh
                h8 ag[RPW + 2][3];
#pragma unroll
                for (int r = 0; r < RPW + 2; ++r)
#pragma unroll
                    for (int mt = 0; mt < 3; ++mt) {
                        const int px = mt * 16 + l16 + kw;
                        ag[r][mt] = *(const h8*)(la +
                            ((size_t)(wave * RPW + r) * 50 + px) * 64 +
                            ((q ^ (px & 7)) << 3));
                    }
                // B(kh=1) in flight before kh=0's MFMAs
#pragma unroll
                for (int nt = 0; nt < 4; ++nt)
                    b[1][nt] = *(const h8*)(wkd + (size_t)(3 + kw) * 4096 + (q << 9) +
                                            ((nt * 16 + l16) << 3));
                // kh = 0
#pragma unroll
                for (int rr = 0; rr < RPW; ++rr)
#pragma unroll
                    for (int mt = 0; mt < 3; ++mt)
#pragma unroll
                        for (int nt = 0; nt < 4; ++nt)
                            acc[rr][mt][nt] = __builtin_amdgcn_mfma_f32_16x16x32_f16(
                                ag[rr][mt], b[0][nt], acc[rr][mt][nt], 0, 0, 0);
                // B(kh=2) in flight before kh=1's MFMAs
#pragma unroll
                for (int nt = 0; nt < 4; ++nt)
                    b[2][nt] = *(const h8*)(wkd + (size_t)(6 + kw) * 4096 + (q << 9) +
                                            ((nt * 16 + l16) << 3));
                // kh = 1
#pragma unroll
                for (int rr = 0; rr < RPW; ++rr)
#pragma unroll
                    for (int mt = 0; mt < 3; ++mt)
#pragma unroll
                        for (int nt = 0; nt < 4; ++nt)
                            acc[rr][mt][nt] = __builtin_amdgcn_mfma_f32_16x16x32_f16(
                                ag[rr + 1][mt], b[1][nt], acc[rr][mt][nt], 0, 0, 0);
                // kh = 2
#pragma unroll
                for (int rr = 0; rr < RPW; ++rr)
#pragma unroll
                    for (int mt = 0; mt < 3; ++mt)
#pragma unroll
                        for (int nt = 0; nt < 4; ++nt)
                            acc[rr][mt][nt] = __builtin_amdgcn_mfma_f32_16x16x32_f16(
                                ag[rr + 2][mt], b[2][nt], acc[rr][mt][nt], 0, 0, 0);
            }
        }
        __builtin_amdgcn_s_setprio(0);
        // drain this wave's ds_reads BEFORE signaling: after the barrier,
        // every wave's reads of la are complete -> safe to restage.
        asm volatile("s_waitcnt lgkmcnt(0)" ::: "memory");
        __builtin_amdgcn_sched_barrier(0);
        __builtin_amdgcn_s_barrier();    // WAR guard: la reusable
        __builtin_amdgcn_sched_barrier(0);
    }

    // epilogue: scale+bias+relu; D layout: co=l16(+nt*16), px=mt*16+quad*4+reg
    // (kd-end drained barrier => all waves' LDS reads complete)
    if (FINAL) {
#pragma unroll
        for (int nt = 0; nt < 4; ++nt) {
            const int co = nt * 16 + l16;
            const float s = scale[co];
            const float bb = bias[co];
#pragma unroll
            for (int rr = 0; rr < RPW; ++rr) {
                const int h = h0 + wave * RPW + rr;
#pragma unroll
                for (int mt = 0; mt < 3; ++mt) {
                    const int w0 = wb + mt * 16 + quad * 4;  // multiple of 4
                    if (w0 < WW) {
                        f4 v;
#pragma unroll
                        for (int r = 0; r < 4; ++r) {
                            float x = acc[rr][mt][nt][r] * s + bb;
                            v[r] = x > 0.f ? x : 0.f;
                        }
                        *(f4*)((float*)outp + (((size_t)(co * 2 + d)) * HH + h) * WW + w0) = v;
                    }
                }
            }
        }
    } else {
        // LDS bounce: transpose to fp16 rows, then coalesced 1-KB stores.
        // Per h-row region: 48 px x 72 shorts; BROWS x 6,912 B <= LA.
        _Float16* epb = (_Float16*)smem_raw;
#pragma unroll
        for (int nt = 0; nt < 4; ++nt) {
            const int co = nt * 16 + l16;
            const float s = scale[co];
            const float bb = bias[co];
#pragma unroll
            for (int rr = 0; rr < RPW; ++rr) {
                _Float16* ep = epb + (size_t)(wave * RPW + rr) * (48 * 72);
#pragma unroll
                for (int mt = 0; mt < 3; ++mt) {
#pragma unroll
                    for (int r = 0; r < 4; ++r) {
                        float x = acc[rr][mt][nt][r] * s + bb;
                        x = x > 0.f ? x : 0.f;
                        ep[(mt * 16 + quad * 4 + r) * 72 + co] = (_Float16)x;
                    }
                }
            }
        }
        const int lim = (WW - wb) * 8;   // chunk count; 256 for wb=144 else >=384
#pragma unroll
        for (int rr = 0; rr < RPW; ++rr) {
            const int h = h0 + wave * RPW + rr;
            const _Float16* ep = epb + (size_t)(wave * RPW + rr) * (48 * 72);
#pragma unroll
            for (int cv = 0; cv < 6; ++cv) {
                if (cv * 64 < lim) {
                    const int c2 = cv * 64 + lane;
                    const int pxl = c2 >> 3, s = c2 & 7;
                    h8 v = *(const h8*)(ep + pxl * 72 + s * 8);
                    const int P = wb + pxl + 1;
                    *(h8*)((_Float16*)outp + (size_t)d * SLICE +
                           ((size_t)(h + 1) * WP + P) * 64 + ((s ^ (P & 7)) << 3)) = v;
                }
            }
        }
    }
}

// ---------------- launch ---------------------------------------------------
extern "C" void kernel_launch(void* const* d_in, const int* in_sizes, int n_in,
                              void* d_out, int out_size, void* d_ws, size_t ws_size,
                              hipStream_t stream) {
    const float* feat   = (const float*)d_in[0];
    const int*   coors  = (const int*)d_in[1];
    const float* W1     = (const float*)d_in[3];
    const float* scale1 = (const float*)d_in[4];
    const float* bias1  = (const float*)d_in[5];
    const float* W2     = (const float*)d_in[6];
    const float* scale2 = (const float*)d_in[7];
    const float* bias2  = (const float*)d_in[8];
    const float* W3     = (const float*)d_in[9];
    const float* scale3 = (const float*)d_in[10];
    const float* bias3  = (const float*)d_in[11];
    const int nvox = in_sizes[0] / 64;

    // workspace: [A1][win][A2][A3][wt x3]; memset covers A1+win only
    const size_t nA1 = (size_t)D_IN * SLICE;     // fp16 elems
    const size_t nWin = (size_t)D_IN * HH * WW;  // ints
    const size_t nA2 = (size_t)D1 * SLICE;
    const size_t nA3 = (size_t)D2 * SLICE;
    const size_t nWT = (size_t)27 * 64 * 64;     // fp16 elems per set

    _Float16* A1 = (_Float16*)d_ws;
    int* win = (int*)(A1 + nA1);
    _Float16* A2 = (_Float16*)(win + nWin);
    _Float16* A3 = A2 + nA2;
    _Float16* wt1 = A3 + nA3;
    _Float16* wt2 = wt1 + nWT;
    _Float16* wt3 = wt2 + nWT;

    hipMemsetAsync(d_ws, 0, nA1 * sizeof(_Float16) + nWin * sizeof(int), stream);

    const int win_blk = (nvox + 255) / 256;
    prep_k<<<8 + 1296 + win_blk, 256, 0, stream>>>(W1, W2, W3, wt1, A2, A3,
                                                   coors, win, nvox);
    scatter_k<<<(nvox + 3) / 4, 256, 0, stream>>>(feat, coors, win, A1, nvox);

    dim3 blk(256);
    // conv1: A1(10) -> A2(5)   RPW=2: 8-row blocks, 500 blocks @ 2/CU = 1 round
    conv_mfma_k<0, 2><<<dim3(4, 25, D1), blk, 0, stream>>>(A1, A2, wt1, scale1, bias1, D_IN, 2, 1);
    // conv2: A2(5) -> A3(3)    RPW=1: 4-row blocks, 600 blocks
    conv_mfma_k<0, 1><<<dim3(4, 50, D2), blk, 0, stream>>>(A2, A3, wt2, scale2, bias2, D1, 1, 0);
    // conv3: A3(3) -> out planar fp32  RPW=1: 400 blocks
    conv_mfma_k<1, 1><<<dim3(4, 50, D3), blk, 0, stream>>>(A3, (float*)d_out, wt3, scale3, bias3, D2, 2, 1);
}

// Round 14
// 186.057 us; speedup vs baseline: 1.1902x; 1.0061x over previous
//
#include <hip/hip_runtime.h>
#include <cstddef>

// D,H,W,C = 10,200,176,64; convs: (s2,p1) -> (s1,p(0,1,1)) -> (s2,p1)
// Activations channels-last fp16, pixel = 128 B, CHUNK-SWIZZLED within pixel:
//   16B chunk s of pixel at column P stored at position s ^ (P & 7).
// Weights pre-swizzled by co (chunk s of row co at s ^ (co & 7)), staged to
// LDS per tap (B crosses L1/L2 once per block).
//
// R13 -> R14: R11 base (best measured 186.6; R13's kw-major restructure was
// a null) + T1 XCD-AWARE BIJECTIVE BLOCK SWIZZLE (m204 formula -- conv1's
// 500 % 8 != 0 requires the bijective variant). Default dispatch round-robins
// blocks across the 8 XCDs, so hy-adjacent blocks (sharing 2 halo rows per
// A-plane and the same kd planes) land on different per-XCD L2s -> HBM
// re-reads at ~900 cyc instead of L2 hits at ~200. Chunked remap gives each
// XCD a contiguous run of blocks within one d. Everything else byte-identical
// to R11's verified kernel.
#define HH 200
#define WW 176
#define HP 202
#define WP 178
#define D_IN 10
#define D1 5
#define D2 3
#define D3 2
#define SLICE ((size_t)HP * WP * 64)

#define LB_BYTES 8192

typedef _Float16 h8 __attribute__((ext_vector_type(8)));
typedef float f4 __attribute__((ext_vector_type(4)));

__device__ __forceinline__ void gl_lds16(const void* g, void* l) {
    __builtin_amdgcn_global_load_lds(
        (const __attribute__((address_space(1))) void*)g,
        (__attribute__((address_space(3))) void*)l, 16, 0, 0);
}

// ---- prep: halo-zero A2/A3 + weight transform (3 sets) + winner, one launch
// blocks [0,8): halo; [8, 8+1296): wtrans; [1304, ...): winner
__global__ __launch_bounds__(256) void prep_k(const float* __restrict__ W1,
                                              const float* __restrict__ W2,
                                              const float* __restrict__ W3,
                                              _Float16* __restrict__ wdst,
                                              _Float16* __restrict__ A2,
                                              _Float16* __restrict__ A3,
                                              const int* __restrict__ coors,
                                              int* __restrict__ winner, int nvox) {
    const int b = blockIdx.x;
    if (b < 8) {
        _Float16* base = (b < D1) ? (A2 + (size_t)b * SLICE) : (A3 + (size_t)(b - D1) * SLICE);
        const h8 z = {};
        for (int t = threadIdx.x; t < 6080; t += 256) {
            size_t off;
            if (t < 2848) {
                int r = t / 1424, c = t - r * 1424;
                off = (size_t)(r ? (HP - 1) : 0) * WP * 64 + (size_t)c * 8;
            } else {
                int u = t - 2848;
                int c = u / 1616, v = u - c * 1616;
                int hr = v >> 3, o = v & 7;
                off = ((size_t)hr * WP + (c ? (WP - 1) : 0)) * 64 + (size_t)o * 8;
            }
            *(h8*)(base + off) = z;
        }
    } else if (b < 8 + 1296) {
        // OIDHW fp32 -> [set][tap][co][ci swizzled] fp16 (B staged verbatim,
        // chunk s of row co stored at s ^ (co & 7) for conflict-free LDS reads)
        int idx = (b - 8) * 256 + threadIdx.x;
        if (idx < 3 * 27 * 64 * 64) {
            int set = idx / 110592;
            int r = idx - set * 110592;
            const float* src = set == 0 ? W1 : (set == 1 ? W2 : W3);
            int ci = r & 63;
            int co = (r >> 6) & 63;
            int tap = r >> 12;
            int s = ci >> 3, j = ci & 7;
            wdst[set * 110592 + tap * 4096 + co * 64 + (((s ^ (co & 7)) << 3) | j)] =
                (_Float16)src[(co * 64 + ci) * 27 + tap];
        }
    } else {
        int v = (b - 1304) * 256 + threadIdx.x;
        if (v < nvox) {
            int d = coors[v * 4 + 1], h = coors[v * 4 + 2], w = coors[v * 4 + 3];
            atomicMax(&winner[(d * HH + h) * WW + w], v + 1);
        }
    }
}

__global__ __launch_bounds__(256) void scatter_k(const float* __restrict__ feat,
                                                 const int* __restrict__ coors,
                                                 const int* __restrict__ winner,
                                                 _Float16* __restrict__ A, int nvox) {
    int v = blockIdx.x * 4 + (threadIdx.x >> 6);
    int ci = threadIdx.x & 63;
    if (v >= nvox) return;
    int d = coors[v * 4 + 1], h = coors[v * 4 + 2], w = coors[v * 4 + 3];
    if (winner[(d * HH + h) * WW + w] != v + 1) return;
    int P = w + 1;
    int swz = (((ci >> 3) ^ (P & 7)) << 3) | (ci & 7);
    A[(size_t)d * SLICE + ((size_t)(h + 1) * WP + P) * 64 + swz] = (_Float16)feat[v * 64 + ci];
}

// ---- MFMA conv: 4-wave block, RPW rows/wave, B-LDS counted-vmcnt pipeline --
// Block = 4 waves; wave i -> RPW output rows, 48 px, 64 co.
// Block index XCD-swizzled (bijective, m204): each XCD gets a contiguous
// run of original block ids -> hy-neighbors (sharing A halo rows + kd
// planes) hit the same per-XCD L2.
// Per kd: stage A ((4*RPW+2) rows x 50 px glds over 4 waves) + B tap0 (8);
// then 9 taps: stage B(t+1) (2 glds/wave), s_waitcnt vmcnt(2) [own B(t)
// landed], s_barrier, 24*RPW MFMA, lgkmcnt(0) drain, s_barrier (WAR guard).
// mfma_f32_16x16x32_f16: A[m=lane&15][k=quad*8+j], D: co=lane&15, px=quad*4+reg
template <int FINAL, int RPW>
__global__ __launch_bounds__(256, 2) void conv_mfma_k(
    const _Float16* __restrict__ in, void* __restrict__ outp,
    const _Float16* __restrict__ wt,
    const float* __restrict__ scale, const float* __restrict__ bias,
    int inD, int strideD, int padD) {
    constexpr int BROWS = 4 * RPW;                  // output rows per block
    constexpr int AR = BROWS + 2;                   // staged input rows
    constexpr int NSTG = (AR * 400 + 63) / 64;      // A chunks: 63 / 38
    constexpr int LA = NSTG * 1024;                 // 64512 / 38912 (incl pad)
    constexpr int CMAX = AR * 400 - 1;
    constexpr int NY = (RPW == 2) ? 25 : 50;        // grid y extent

    __shared__ char smem_raw[LA + 2 * LB_BYTES];
    _Float16* la = (_Float16*)smem_raw;
    char* lb0 = smem_raw + LA;
    char* lb1 = smem_raw + LA + LB_BYTES;

    const int lane = threadIdx.x & 63;
    const int wave = threadIdx.x >> 6;   // 0..3
    const int l16 = lane & 15;
    const int quad = lane >> 4;

    // T1: bijective XCD swizzle of the flattened block id (perf-only remap).
    // orig -> (xcd = orig&7, slot = orig>>3); XCD k owns a contiguous chunk.
    const int nwg = 4 * NY * gridDim.z;
    const int orig = blockIdx.x + 4 * (blockIdx.y + NY * blockIdx.z);
    const int q = nwg >> 3, r = nwg & 7;
    const int xcd = orig & 7, slot = orig >> 3;
    int wgid = (xcd < r ? xcd * (q + 1) : r * (q + 1) + (xcd - r) * q) + slot;
    const int bx = wgid & 3;
    const int rest = wgid >> 2;
    const int by = rest % NY;
    const int bz = rest / NY;

    const int h0 = by * BROWS;
    const int wb = bx * 48;              // 48 | 8 so (wb+px)&7 == px&7
    const int d = bz;

    int kd_lo = padD - d * strideD; if (kd_lo < 0) kd_lo = 0;
    int kd_hi = inD - 1 - d * strideD + padD; if (kd_hi > 2) kd_hi = 2;

    f4 acc[RPW][3][4];
#pragma unroll
    for (int rr = 0; rr < RPW; ++rr)
#pragma unroll
        for (int mt = 0; mt < 3; ++mt)
#pragma unroll
            for (int nt = 0; nt < 4; ++nt) acc[rr][mt][nt] = (f4){0.f, 0.f, 0.f, 0.f};

    for (int kd = kd_lo; kd <= kd_hi; ++kd) {
        const int zd = d * strideD + kd - padD;
        const _Float16* __restrict__ aplane = in + (size_t)zd * SLICE;
        const _Float16* __restrict__ wkd = wt + (size_t)kd * 9 * 4096;

        // stage A: AR rows x 50 px x 8 chunks -> NSTG instrs over 4 waves
        // (WAR vs previous kd's reads guarded by the t=8 lgkm-drained barrier)
        for (int j = wave; j < NSTG; j += 4) {
            int c = j * 64 + lane;
            if (c > CMAX) c = CMAX;            // dup into pad
            int r2 = c / 400;
            int rem = c - r2 * 400;
            int px = rem >> 3, s = rem & 7;
            int g = wb + px; if (g > 177) g = 177;  // ragged edge dup
            gl_lds16(aplane + ((size_t)(h0 + r2) * WP + g) * 64 + s * 8,
                     smem_raw + j * 1024);
        }
        // stage B tap 0 into lb0 (2 instrs/wave)
#pragma unroll
        for (int i = 0; i < 2; ++i) {
            int k = i * 4 + wave;
            gl_lds16(wkd + (size_t)(k * 64 + lane) * 8, lb0 + k * 1024);
        }

#pragma unroll
        for (int t = 0; t < 9; ++t) {    // tap = kh*3 + kw
            const int kh = t / 3;
            const int kw = t - 3 * kh;
            char* lbc = (t & 1) ? lb1 : lb0;      // t is unroll-constant

            if (t < 8) {
                // stage B(t+1): tap stride 4096 ELEMENTS (R5/R6 lesson)
                char* lbn = (t & 1) ? lb0 : lb1;
#pragma unroll
                for (int i = 0; i < 2; ++i) {
                    int k = i * 4 + wave;
                    gl_lds16(wkd + (size_t)(t + 1) * 4096 + (size_t)(k * 64 + lane) * 8,
                             lbn + k * 1024);
                }
                asm volatile("s_waitcnt vmcnt(2)" ::: "memory");  // B(t)+older done
            } else {
                asm volatile("s_waitcnt vmcnt(0)" ::: "memory");
            }
            __builtin_amdgcn_sched_barrier(0);
            __builtin_amdgcn_s_barrier();    // all waves' stages visible
            __builtin_amdgcn_sched_barrier(0);  // nothing hoists above barrier

            const _Float16* lb = (const _Float16*)lbc;
            __builtin_amdgcn_s_setprio(1);
#pragma unroll
            for (int ch = 0; ch < 2; ++ch) {
                const int q2 = ch * 4 + quad;
                h8 b[4];
#pragma unroll
                for (int nt = 0; nt < 4; ++nt)
                    b[nt] = *(const h8*)(lb + (nt * 16 + l16) * 64 +
                                         ((q2 ^ (l16 & 7)) << 3));
#pragma unroll
                for (int rr = 0; rr < RPW; ++rr) {
                    const int row = wave * RPW + rr + kh;
#pragma unroll
                    for (int mt = 0; mt < 3; ++mt) {
                        const int px = mt * 16 + l16 + kw;
                        h8 a = *(const h8*)(la + ((size_t)row * 50 + px) * 64 +
                                            ((q2 ^ (px & 7)) << 3));
#pragma unroll
                        for (int nt = 0; nt < 4; ++nt)
                            acc[rr][mt][nt] = __builtin_amdgcn_mfma_f32_16x16x32_f16(
                                a, b[nt], acc[rr][mt][nt], 0, 0, 0);
                    }
                }
            }
            __builtin_amdgcn_s_setprio(0);
            // drain this wave's ds_reads BEFORE signaling: after the barrier,
            // every wave's reads of la/lb are complete -> safe to overwrite.
            asm volatile("s_waitcnt lgkmcnt(0)" ::: "memory");
            __builtin_amdgcn_sched_barrier(0);
            __builtin_amdgcn_s_barrier();    // WAR guard: lb[(t+1)&1]/la reusable
            __builtin_amdgcn_sched_barrier(0);
        }
    }

    // epilogue: scale+bias+relu; D layout: co=l16(+nt*16), px=mt*16+quad*4+reg
    // (last tap's lgkm-drained barrier => all waves' LDS reads complete)
    if (FINAL) {
#pragma unroll
        for (int nt = 0; nt < 4; ++nt) {
            const int co = nt * 16 + l16;
            const float s = scale[co];
            const float bb = bias[co];
#pragma unroll
            for (int rr = 0; rr < RPW; ++rr) {
                const int h = h0 + wave * RPW + rr;
#pragma unroll
                for (int mt = 0; mt < 3; ++mt) {
                    const int w0 = wb + mt * 16 + quad * 4;  // multiple of 4
                    if (w0 < WW) {
                        f4 v;
#pragma unroll
                        for (int r2 = 0; r2 < 4; ++r2) {
                            float x = acc[rr][mt][nt][r2] * s + bb;
                            v[r2] = x > 0.f ? x : 0.f;
                        }
                        *(f4*)((float*)outp + (((size_t)(co * 2 + d)) * HH + h) * WW + w0) = v;
                    }
                }
            }
        }
    } else {
        // LDS bounce: transpose to fp16 rows, then coalesced 1-KB stores.
        // Per h-row region: 48 px x 72 shorts; BROWS x 6,912 B <= LA.
        _Float16* epb = (_Float16*)smem_raw;
#pragma unroll
        for (int nt = 0; nt < 4; ++nt) {
            const int co = nt * 16 + l16;
            const float s = scale[co];
            const float bb = bias[co];
#pragma unroll
            for (int rr = 0; rr < RPW; ++rr) {
                _Float16* ep = epb + (size_t)(wave * RPW + rr) * (48 * 72);
#pragma unroll
                for (int mt = 0; mt < 3; ++mt) {
#pragma unroll
                    for (int r2 = 0; r2 < 4; ++r2) {
                        float x = acc[rr][mt][nt][r2] * s + bb;
                        x = x > 0.f ? x : 0.f;
                        ep[(mt * 16 + quad * 4 + r2) * 72 + co] = (_Float16)x;
                    }
                }
            }
        }
        const int lim = (WW - wb) * 8;   // chunk count; 256 for wb=144 else >=384
#pragma unroll
        for (int rr = 0; rr < RPW; ++rr) {
            const int h = h0 + wave * RPW + rr;
            const _Float16* ep = epb + (size_t)(wave * RPW + rr) * (48 * 72);
#pragma unroll
            for (int cv = 0; cv < 6; ++cv) {
                if (cv * 64 < lim) {
                    const int c2 = cv * 64 + lane;
                    const int pxl = c2 >> 3, s = c2 & 7;
                    h8 v = *(const h8*)(ep + pxl * 72 + s * 8);
                    const int P = wb + pxl + 1;
                    *(h8*)((_Float16*)outp + (size_t)d * SLICE +
                           ((size_t)(h + 1) * WP + P) * 64 + ((s ^ (P & 7)) << 3)) = v;
                }
            }
        }
    }
}

// ---------------- launch ---------------------------------------------------
extern "C" void kernel_launch(void* const* d_in, const int* in_sizes, int n_in,
                              void* d_out, int out_size, void* d_ws, size_t ws_size,
                              hipStream_t stream) {
    const float* feat   = (const float*)d_in[0];
    const int*   coors  = (const int*)d_in[1];
    const float* W1     = (const float*)d_in[3];
    const float* scale1 = (const float*)d_in[4];
    const float* bias1  = (const float*)d_in[5];
    const float* W2     = (const float*)d_in[6];
    const float* scale2 = (const float*)d_in[7];
    const float* bias2  = (const float*)d_in[8];
    const float* W3     = (const float*)d_in[9];
    const float* scale3 = (const float*)d_in[10];
    const float* bias3  = (const float*)d_in[11];
    const int nvox = in_sizes[0] / 64;

    // workspace: [A1][win][A2][A3][wt x3]; memset covers A1+win only
    const size_t nA1 = (size_t)D_IN * SLICE;     // fp16 elems
    const size_t nWin = (size_t)D_IN * HH * WW;  // ints
    const size_t nA2 = (size_t)D1 * SLICE;
    const size_t nA3 = (size_t)D2 * SLICE;
    const size_t nWT = (size_t)27 * 64 * 64;     // fp16 elems per set

    _Float16* A1 = (_Float16*)d_ws;
    int* win = (int*)(A1 + nA1);
    _Float16* A2 = (_Float16*)(win + nWin);
    _Float16* A3 = A2 + nA2;
    _Float16* wt1 = A3 + nA3;
    _Float16* wt2 = wt1 + nWT;
    _Float16* wt3 = wt2 + nWT;

    hipMemsetAsync(d_ws, 0, nA1 * sizeof(_Float16) + nWin * sizeof(int), stream);

    const int win_blk = (nvox + 255) / 256;
    prep_k<<<8 + 1296 + win_blk, 256, 0, stream>>>(W1, W2, W3, wt1, A2, A3,
                                                   coors, win, nvox);
    scatter_k<<<(nvox + 3) / 4, 256, 0, stream>>>(feat, coors, win, A1, nvox);

    dim3 blk(256);
    // conv1: A1(10) -> A2(5)   RPW=2: 8-row blocks, 500 blocks @ 2/CU = 1 round
    conv_mfma_k<0, 2><<<dim3(4, 25, D1), blk, 0, stream>>>(A1, A2, wt1, scale1, bias1, D_IN, 2, 1);
    // conv2: A2(5) -> A3(3)    RPW=1: 4-row blocks, 600 blocks
    conv_mfma_k<0, 1><<<dim3(4, 50, D2), blk, 0, stream>>>(A2, A3, wt2, scale2, bias2, D1, 1, 0);
    // conv3: A3(3) -> out planar fp32  RPW=1: 400 blocks
    conv_mfma_k<1, 1><<<dim3(4, 50, D3), blk, 0, stream>>>(A3, (float*)d_out, wt3, scale3, bias3, D2, 2, 1);
}